// Round 9
// baseline (355.499 us; speedup 1.0000x reference)
//
#include <hip/hip_runtime.h>
#include <hip/hip_bf16.h>

typedef __attribute__((ext_vector_type(8))) short bfrag;   // 8 x bf16 (4 VGPRs)
typedef __attribute__((ext_vector_type(4))) float ffrag;   // 4 x f32 acc

#define NB 1024
#define NT 256
#define RB 8   // rows per block (R20: 16 -> 8, 128 blocks)

// -log2(e), -2*log2(e): folded into weights so S2 needs no per-activation mul.
#define KSIG -1.44269504f
#define KTAN -2.88539008f

static __device__ __forceinline__ float fast_rcp(float x) { return __builtin_amdgcn_rcpf(x); }
// unscaled (logit path only)
static __device__ __forceinline__ float sigm(float x) {
  return fast_rcp(1.f + __builtin_amdgcn_exp2f(-1.44269504f * x));
}
// pre-scaled args (weights already multiplied by KSIG/KTAN)
static __device__ __forceinline__ float sigm_pre(float s) {
  return fast_rcp(1.f + __builtin_amdgcn_exp2f(s));
}
static __device__ __forceinline__ float tanh_pre(float s) {
  return __builtin_fmaf(2.f, fast_rcp(1.f + __builtin_amdgcn_exp2f(s)), -1.f);
}
static __device__ __forceinline__ float tanh_f(float x) {
  return __builtin_fmaf(2.f, fast_rcp(1.f + __builtin_amdgcn_exp2f(-2.88539008f * x)), -1.f);
}
static __device__ __forceinline__ float bf2f(__hip_bfloat16 v) { return __bfloat162float(v); }
static __device__ __forceinline__ short f2bs(float f) {
  __hip_bfloat16 h = __float2bfloat16(f);
  return *reinterpret_cast<short*>(&h);
}
// LDS-only barrier: skip the vmcnt(0) drain __syncthreads would force.
static __device__ __forceinline__ void barrier_lgkm() {
  asm volatile("s_waitcnt lgkmcnt(0)\n\ts_barrier" ::: "memory");
}

// ---------------------------------------------------------------------------
// R20 = R18 (verified ~265us kernel) parameterized 16 -> 8 rows/block
// (128 blocks). Rationale from R19 counters: matrix pipe is at its issue
// floor (670 cyc/step = 27% active-CU MfmaUtil); step time is VALU-dominated
// (44%) and VALU scales with rows/block, MFMA does not. Pure parameter
// change, NO restructure (cursed grid-256 family used compaction + new
// primitives; this does not):
//  - h_bf stays [2][16][136]; rows 8-15 zeroed once, read as zero A-rows.
//  - S2 / h-init / output stores guarded ldiv<2 (upper 32 lanes fully
//    exec-masked -> SIMD-32 upper pass skippable).
//  - gathers clamp row with (lmod&7); C rows 8-15 are garbage-but-unused.
//  - all staging (eps/y/id) halved; eps_ch row dim 16 -> 8.
// ---------------------------------------------------------------------------
__global__ __launch_bounds__(512, 2) void gru_kernel(
    const float* __restrict__ x,     // [B,64]
    const int* __restrict__ a_ids,   // [B,T]
    const int* __restrict__ t_ids,   // [B,T]
    const float* __restrict__ y,     // [B,T]
    const float* __restrict__ eps,   // [B,T,16]
    const float* __restrict__ Wx,    // [64,64]
    const float* __restrict__ bx,    // [64]
    const float* __restrict__ Ea,    // [100,32]
    const float* __restrict__ Et,    // [4,16]
    const float* __restrict__ Wih,   // [384,129]
    const float* __restrict__ Whh,   // [384,128]
    const float* __restrict__ bih,   // [384]
    const float* __restrict__ bhh,   // [384]
    const float* __restrict__ W0,    // [128,80]
    const float* __restrict__ b0g,   // [128]
    const float* __restrict__ Wy,    // [1,128]
    const float* __restrict__ by,    // [1]
    float* __restrict__ out)         // [B,T,2]
{
  // ---- persistent LDS ----
  __shared__ __align__(16) __hip_bfloat16 h_bf[2][16][136];  // rows 8-15 stay 0
  __shared__ __align__(16) __hip_bfloat16 Ea_s[100][40];     // padded rows (data in cols 0..31)
  __shared__ __align__(16) __hip_bfloat16 Et_s[4][16];
  __shared__ float prevy_s[2][RB];
  __shared__ float bsum_r[128], bsum_z[128], bihn_s[128], bhhn_s[128];  // pre-scaled
  __shared__ float wprev_s[384];                                        // pre-scaled
  // ---- unioned region (33408 B) ----
  // persistent: id_s[256][8]u16 @0 (4096) | eps_ch[2][16][8][24]bf16 @4096 (12288)
  //             y_ch[2][8][16]f32 @16384 (1024)
  // prologue:   Wxb[64][64]bf16 @0 (8192) | W0b[128][80]bf16 @8192 (20480)
  //             x_s[8][65]f32 @28672 | eps0s[8][17]f32 @30752 | xe_s[8][65]f32 @31296
  //             h0f[8][128]f32 @0 (after Wxb dead)
  __shared__ __align__(16) char uni[33408];
  unsigned short* id_s    = (unsigned short*)(uni);
  __hip_bfloat16* eps_ch  = (__hip_bfloat16*)(uni + 4096);
  float*          y_ch    = (float*)(uni + 16384);
  __hip_bfloat16* Wxb     = (__hip_bfloat16*)(uni);
  __hip_bfloat16* W0b     = (__hip_bfloat16*)(uni + 8192);
  float*          x_s     = (float*)(uni + 28672);
  float*          eps0s   = (float*)(uni + 30752);
  float*          xe_s    = (float*)(uni + 31296);
  float*          h0f     = (float*)(uni);

  const int tid = threadIdx.x;
  const int w = tid >> 6, l = tid & 63;
  const int lmod = l & 15, ldiv = l >> 4;
  const int i_own = 16 * w + lmod;
  const int b0 = blockIdx.x * RB;

  // ================= PROLOGUE =================
  // zero h_bf once: rows 8-15 of both buffers must read as 0 A-rows forever.
  for (int j = tid; j < 1088; j += 512) ((unsigned long long*)h_bf)[j] = 0ULL;
  if (tid < 128) {
    bsum_r[tid] = KSIG * (bih[tid] + bhh[tid]);
    bsum_z[tid] = KSIG * (bih[128 + tid] + bhh[128 + tid]);
    bihn_s[tid] = KTAN * bih[256 + tid];
    bhhn_s[tid] = KTAN * bhh[256 + tid];
  }
  if (tid < 384) wprev_s[tid] = ((tid < 256) ? KSIG : KTAN) * Wih[tid * 129 + 128];
  for (int j = tid; j < 3200; j += 512) {
    int r = j >> 5, c = j & 31;
    Ea_s[r][c] = __float2bfloat16(Ea[j]);
  }
  if (tid < 64) ((__hip_bfloat16*)Et_s)[tid] = __float2bfloat16(Et[tid]);
  for (int j = tid; j < 4096; j += 512)  Wxb[j] = __float2bfloat16(Wx[j]);
  for (int j = tid; j < 10240; j += 512) W0b[j] = __float2bfloat16(W0[j]);
  if (tid < 512) {
    int r = tid >> 6, c = tid & 63;   // 8 rows x 64 cols
    x_s[r * 65 + c] = x[(b0 + r) * 64 + c];
  }
  if (tid < 128) {
    int r = tid >> 4, c = tid & 15;   // 8 rows x 16 ch
    eps0s[r * 17 + c] = eps[((b0 + r) * NT) * 16 + c];
  }
  const float by_f = by[0];

  // persistent B-frags: wave w owns gate-cols i_own of r/z/n. Pre-scaled.
  bfrag Bh[3][4], Bi[3][2];
  #pragma unroll
  for (int g = 0; g < 3; g++) {
    const float sg = (g < 2) ? KSIG : KTAN;
    int n = (g * 8 + w) * 16 + lmod;
    #pragma unroll
    for (int kc = 0; kc < 4; kc++) {
      int k = kc * 32 + ldiv * 8;
      const float* wh = Whh + n * 128 + k;
      float4 h0v = *reinterpret_cast<const float4*>(wh);
      float4 h1v = *reinterpret_cast<const float4*>(wh + 4);
      bfrag th = {f2bs(sg * h0v.x), f2bs(sg * h0v.y), f2bs(sg * h0v.z), f2bs(sg * h0v.w),
                  f2bs(sg * h1v.x), f2bs(sg * h1v.y), f2bs(sg * h1v.z), f2bs(sg * h1v.w)};
      Bh[g][kc] = th;
    }
    #pragma unroll
    for (int kc = 0; kc < 2; kc++) {
      bfrag ti;
      #pragma unroll
      for (int j = 0; j < 8; j++) {
        int dk = kc * 32 + ldiv * 8 + j;
        int col = dk < 48 ? dk : dk + 64;
        ti[j] = f2bs(sg * Wih[n * 129 + col]);
      }
      Bi[g][kc] = ti;
    }
  }
  // logit B-tile for wave 7: col 0 = Wy, other cols 0 (UNscaled)
  bfrag Bl[4];
  if (w == 7) {
    #pragma unroll
    for (int kc = 0; kc < 4; kc++) {
      bfrag bt;
      #pragma unroll
      for (int j = 0; j < 8; j++)
        bt[j] = (lmod == 0) ? f2bs(Wy[kc * 32 + ldiv * 8 + j]) : (short)0;
      Bl[kc] = bt;
    }
  }
  __syncthreads();  // B1: x_s, Wxb, tables ready (h_bf zeroed)

  // ph1: xenc = x@Wx.T + bx -> xe_s (f32) + xdyn bf16 (h_bf[1] rows 0-7)
  if (tid < 512) {
    int r = tid & 7, i = tid >> 3;   // 8 rows x 64 cols
    float acc = bx[i];
    #pragma unroll 8
    for (int k = 0; k < 64; k++) acc += x_s[r * 65 + k] * bf2f(Wxb[i * 64 + k]);
    xe_s[r * 65 + i] = acc;
    h_bf[1][r][i] = __float2bfloat16(acc);
  }
  __syncthreads();  // B2: xe_s + xdyn ready; Wxb dead

  // ph2: h0 = tanh([xenc,eps0]@W0.T + b0) -> h0f (overwrites Wxb region)
  for (int j = tid; j < 1024; j += 512) {
    int r = j & 7, o = j >> 3;       // 8 rows x 128 h-dims
    float acc = b0g[o];
    #pragma unroll 8
    for (int k = 0; k < 64; k++) acc += xe_s[r * 65 + k] * bf2f(W0b[o * 80 + k]);
    #pragma unroll
    for (int k = 0; k < 16; k++) acc += eps0s[r * 17 + k] * bf2f(W0b[o * 80 + 64 + k]);
    h0f[r * 128 + o] = tanh_f(acc);
  }

  // gxc = scaled( xenc @ Wih[:,48:112].T + per-gate biases )
  ffrag gxc[3];
  {
    ffrag z = {0.f, 0.f, 0.f, 0.f};
    gxc[0] = z; gxc[1] = z; gxc[2] = z;
    #pragma unroll
    for (int kc = 0; kc < 2; kc++) {
      bfrag axd = *reinterpret_cast<const bfrag*>(&h_bf[1][lmod][kc * 32 + ldiv * 8]);
      #pragma unroll
      for (int g = 0; g < 3; g++) {
        const float sg = (g < 2) ? KSIG : KTAN;
        int n = (g * 8 + w) * 16 + lmod;
        const float* wi = Wih + n * 129 + 48 + kc * 32 + ldiv * 8;
        bfrag bt;
        #pragma unroll
        for (int j = 0; j < 8; j++) bt[j] = f2bs(sg * wi[j]);
        gxc[g] = __builtin_amdgcn_mfma_f32_16x16x32_bf16(axd, bt, gxc[g], 0, 0, 0);
      }
    }
    float brf = bsum_r[i_own], bzf = bsum_z[i_own], bn1 = bihn_s[i_own];
    #pragma unroll
    for (int q = 0; q < 4; q++) {
      gxc[0][q] += brf;
      gxc[1][q] += bzf;
      gxc[2][q] += bn1;
    }
  }
  __syncthreads();  // B3: h0f complete; gxc done

  // h init: fp32 regs + bf16 mirror (rows 0-7 only; ldiv<2)
  float h_reg[4] = {0.f, 0.f, 0.f, 0.f};
  if (ldiv < 2) {
    #pragma unroll
    for (int q = 0; q < 4; q++) {
      int row = ldiv * 4 + q;
      float hv = h0f[row * 128 + i_own];
      h_reg[q] = hv;
      h_bf[0][row][i_own] = __float2bfloat16(hv);
    }
  }
  __syncthreads();  // B4: h0f dead; uni becomes persistent

  // ids (packed, [t][row]) + chunk 0 of eps/y
  for (int j = tid; j < 2048; j += 512) {
    int r = j >> 8, t = j & 255;     // 8 rows
    unsigned short v = (unsigned short)(a_ids[(b0 + r) * NT + t] |
                                        (t_ids[(b0 + r) * NT + t] << 8));
    id_s[t * RB + r] = v;
  }
  if (tid < 256) {
    int r = tid >> 5, sub = tid & 31;  // 8 rows x 32 sub
    const float* p = eps + ((b0 + r) * NT) * 16 + sub * 8;
    float4 eA = *reinterpret_cast<const float4*>(p);
    float4 eB = *reinterpret_cast<const float4*>(p + 4);
    int toff = sub >> 1, c8 = (sub & 1) * 8;
    bfrag e = {f2bs(eA.x), f2bs(eA.y), f2bs(eA.z), f2bs(eA.w),
               f2bs(eB.x), f2bs(eB.y), f2bs(eB.z), f2bs(eB.w)};
    *reinterpret_cast<bfrag*>(&eps_ch[((0 * 16 + toff) * RB + r) * 24 + c8]) = e;
    if (tid < 32) {
      int r2 = tid >> 2, s2 = tid & 3;  // 8 rows x 4 quads
      float4 yv = *reinterpret_cast<const float4*>(y + (b0 + r2) * NT + s2 * 4);
      *reinterpret_cast<float4*>(&y_ch[r2 * 16 + s2 * 4]) = yv;
    }
  }
  if (tid < RB) prevy_s[0][tid] = 0.f;
  // hoisted per-lane constants (pre-scaled)
  const float wpr = wprev_s[i_own], wpz = wprev_s[128 + i_own], wpn = wprev_s[256 + i_own];
  const float bn2 = bhhn_s[i_own];
  // hoisted per-lane address pieces for the direct dyn-input gather
  const char* const ea_base  = (const char*)Ea_s + ldiv * 16;
  const char* const et_base  = (const char*)Et_s + ldiv * 16;
  const char* const eps_base = (const char*)eps_ch + (lmod & 7) * 48 + (ldiv - 2) * 16;
  __syncthreads();  // B5: id_s / eps_ch chunk0 / y_ch ready

  // input-gate MFMAs for t=0
  ffrag pa0 = gxc[0], pa1 = gxc[1], pa2 = gxc[2];
  {
    int id = id_s[lmod & 7];
    int aid = id & 127, tv = id >> 8;
    bfrag axA = *reinterpret_cast<const bfrag*>(ea_base + aid * 80);
    const char* etp = et_base + tv * 32;
    const char* epp = eps_base;  // t=0: cbn=0, tm=0
    bfrag axB = *reinterpret_cast<const bfrag*>(ldiv < 2 ? etp : epp);
    pa0 = __builtin_amdgcn_mfma_f32_16x16x32_bf16(axA, Bi[0][0], pa0, 0, 0, 0);
    pa1 = __builtin_amdgcn_mfma_f32_16x16x32_bf16(axA, Bi[1][0], pa1, 0, 0, 0);
    pa2 = __builtin_amdgcn_mfma_f32_16x16x32_bf16(axA, Bi[2][0], pa2, 0, 0, 0);
    pa0 = __builtin_amdgcn_mfma_f32_16x16x32_bf16(axB, Bi[0][1], pa0, 0, 0, 0);
    pa1 = __builtin_amdgcn_mfma_f32_16x16x32_bf16(axB, Bi[1][1], pa1, 0, 0, 0);
    pa2 = __builtin_amdgcn_mfma_f32_16x16x32_bf16(axB, Bi[2][1], pa2, 0, 0, 0);
  }

  // ================= MAIN LOOP =================
  for (int t = 0; t < NT; t++) {
    const int buf = t & 1, nbuf = buf ^ 1;

    // issue next-chunk global loads (rare)
    const bool ck = ((t & 15) == 0) && (t + 16 < NT);
    float4 eA, eB, yv;
    const int cr = tid >> 5, csub = tid & 31;
    if (ck && tid < 256) {
      const float* p = eps + ((b0 + cr) * NT + t + 16) * 16 + csub * 8;
      eA = *reinterpret_cast<const float4*>(p);
      eB = *reinterpret_cast<const float4*>(p + 4);
      if (tid < 32) {
        int r2 = tid >> 2, s2 = tid & 3;
        yv = *reinterpret_cast<const float4*>(y + (b0 + r2) * NT + t + 16 + s2 * 4);
      }
    }

    // h-MFMAs: the only barrier-dependent work
    ffrag anh, agl;
    #pragma unroll
    for (int q = 0; q < 4; q++) anh[q] = bn2;
    if (w == 7) {
      #pragma unroll
      for (int q = 0; q < 4; q++) agl[q] = by_f;
    }
    #pragma unroll
    for (int kc = 0; kc < 4; kc++) {
      bfrag ah = *reinterpret_cast<const bfrag*>(&h_bf[buf][lmod][kc * 32 + ldiv * 8]);
      pa0 = __builtin_amdgcn_mfma_f32_16x16x32_bf16(ah, Bh[0][kc], pa0, 0, 0, 0);
      pa1 = __builtin_amdgcn_mfma_f32_16x16x32_bf16(ah, Bh[1][kc], pa1, 0, 0, 0);
      anh = __builtin_amdgcn_mfma_f32_16x16x32_bf16(ah, Bh[2][kc], anh, 0, 0, 0);
      if (w == 7)
        agl = __builtin_amdgcn_mfma_f32_16x16x32_bf16(ah, Bl[kc], agl, 0, 0, 0);
    }

    // prevy for t+1 (wave 6, 8 lanes)
    if (tid >= 384 && tid < 384 + RB) {
      int r = tid - 384;
      prevy_s[nbuf][r] = y_ch[((t >> 4) & 1) * (RB * 16) + r * 16 + (t & 15)];
    }

    // wave 7: logit/prob for step t-1 -> DIRECT global float2 stores (rows 0-7)
    if (w == 7 && t > 0 && lmod == 0 && ldiv < 2) {
      #pragma unroll
      for (int q = 0; q < 4; q++) {
        int row = ldiv * 4 + q;
        float lg = agl[q];
        float2 v;
        v.x = lg;
        v.y = sigm(lg);
        *reinterpret_cast<float2*>(out + ((b0 + row) * NT + (t - 1)) * 2) = v;
      }
    }

    // S2: gates, h update — rows 0-7 only (upper 32 lanes fully masked)
    if (ldiv < 2) {
      #pragma unroll
      for (int q = 0; q < 4; q++) {
        int row = ldiv * 4 + q;
        float py = prevy_s[buf][row];
        float rv = sigm_pre(__builtin_fmaf(py, wpr, pa0[q]));
        float zv = sigm_pre(__builtin_fmaf(py, wpz, pa1[q]));
        float nv = tanh_pre(__builtin_fmaf(rv, anh[q], __builtin_fmaf(py, wpn, pa2[q])));
        float hn = __builtin_fmaf(zv, h_reg[q] - nv, nv);
        h_reg[q] = hn;
        h_bf[nbuf][row][i_own] = __float2bfloat16(hn);
      }
    }

    // input-gate MFMAs for t+1 (independent of h_t; hides under barrier)
    if (t + 1 < NT) {
      const int tn = t + 1;
      const int ebase = (((tn >> 4) & 1) * 16 + (tn & 15)) * RB;  // eps row-block
      int id = id_s[tn * RB + (lmod & 7)];
      int aid = id & 127, tv = id >> 8;
      bfrag axA = *reinterpret_cast<const bfrag*>(ea_base + aid * 80);
      const char* etp = et_base + tv * 32;
      const char* epp = eps_base + ebase * 48;
      bfrag axB = *reinterpret_cast<const bfrag*>(ldiv < 2 ? etp : epp);
      pa0 = gxc[0]; pa1 = gxc[1]; pa2 = gxc[2];
      pa0 = __builtin_amdgcn_mfma_f32_16x16x32_bf16(axA, Bi[0][0], pa0, 0, 0, 0);
      pa1 = __builtin_amdgcn_mfma_f32_16x16x32_bf16(axA, Bi[1][0], pa1, 0, 0, 0);
      pa2 = __builtin_amdgcn_mfma_f32_16x16x32_bf16(axA, Bi[2][0], pa2, 0, 0, 0);
      pa0 = __builtin_amdgcn_mfma_f32_16x16x32_bf16(axB, Bi[0][1], pa0, 0, 0, 0);
      pa1 = __builtin_amdgcn_mfma_f32_16x16x32_bf16(axB, Bi[1][1], pa1, 0, 0, 0);
      pa2 = __builtin_amdgcn_mfma_f32_16x16x32_bf16(axB, Bi[2][1], pa2, 0, 0, 0);
    }

    // next-chunk convert + LDS write (rare)
    if (ck && tid < 256) {
      int cb2 = ((t >> 4) + 1) & 1;
      int toff = csub >> 1, c8 = (csub & 1) * 8;
      bfrag e = {f2bs(eA.x), f2bs(eA.y), f2bs(eA.z), f2bs(eA.w),
                 f2bs(eB.x), f2bs(eB.y), f2bs(eB.z), f2bs(eB.w)};
      *reinterpret_cast<bfrag*>(&eps_ch[((cb2 * 16 + toff) * RB + cr) * 24 + c8]) = e;
      if (tid < 32) {
        int r2 = tid >> 2, s2 = tid & 3;
        *reinterpret_cast<float4*>(&y_ch[cb2 * (RB * 16) + r2 * 16 + s2 * 4]) = yv;
      }
    }

    barrier_lgkm();  // the ONE barrier per step (LDS-only drain)
  }

  // ---- tail: logit for step 255 from h_bf[0] (= H_256), direct store ----
  if (w == 7) {
    ffrag agl;
    #pragma unroll
    for (int q = 0; q < 4; q++) agl[q] = by_f;
    #pragma unroll
    for (int kc = 0; kc < 4; kc++) {
      bfrag ah = *reinterpret_cast<const bfrag*>(&h_bf[0][lmod][kc * 32 + ldiv * 8]);
      agl = __builtin_amdgcn_mfma_f32_16x16x32_bf16(ah, Bl[kc], agl, 0, 0, 0);
    }
    if (lmod == 0 && ldiv < 2) {
      #pragma unroll
      for (int q = 0; q < 4; q++) {
        int row = ldiv * 4 + q;
        float lg = agl[q];
        float2 v;
        v.x = lg;
        v.y = sigm(lg);
        *reinterpret_cast<float2*>(out + ((b0 + row) * NT + 255) * 2) = v;
      }
    }
  }
}

extern "C" void kernel_launch(void* const* d_in, const int* in_sizes, int n_in,
                              void* d_out, int out_size, void* d_ws, size_t ws_size,
                              hipStream_t stream) {
  const float* x   = (const float*)d_in[0];
  const int*   a   = (const int*)d_in[1];
  const int*   tt  = (const int*)d_in[2];
  const float* y   = (const float*)d_in[3];
  // d_in[4] = mask: forward output is mask-independent (m*v + (1-m)*v == v)
  const float* eps = (const float*)d_in[5];
  const float* Wx  = (const float*)d_in[6];
  const float* bx  = (const float*)d_in[7];
  const float* Ea  = (const float*)d_in[8];
  const float* Et  = (const float*)d_in[9];
  const float* Wih = (const float*)d_in[10];
  const float* Whh = (const float*)d_in[11];
  const float* bih = (const float*)d_in[12];
  const float* bhh = (const float*)d_in[13];
  const float* W0  = (const float*)d_in[14];
  const float* b0  = (const float*)d_in[15];
  const float* Wy  = (const float*)d_in[16];
  const float* by  = (const float*)d_in[17];
  float* out = (float*)d_out;

  gru_kernel<<<NB / RB, 512, 0, stream>>>(x, a, tt, y, eps, Wx, bx, Ea, Et,
                                          Wih, Whh, bih, bhh, W0, b0, Wy, by, out);
}

// Round 10
// 346.686 us; speedup vs baseline: 1.0254x; 1.0254x over previous
//
#include <hip/hip_runtime.h>
#include <hip/hip_bf16.h>

typedef __attribute__((ext_vector_type(8))) short bfrag;   // 8 x bf16 (4 VGPRs)
typedef __attribute__((ext_vector_type(4))) float ffrag;   // 4 x f32 acc

#define NB 1024
#define NT 256

// -log2(e), -2*log2(e): folded into weights so S2 needs no per-activation mul.
#define KSIG -1.44269504f
#define KTAN -2.88539008f

static __device__ __forceinline__ float fast_rcp(float x) { return __builtin_amdgcn_rcpf(x); }
// unscaled (logit path only)
static __device__ __forceinline__ float sigm(float x) {
  return fast_rcp(1.f + __builtin_amdgcn_exp2f(-1.44269504f * x));
}
// pre-scaled args (weights already multiplied by KSIG/KTAN)
static __device__ __forceinline__ float sigm_pre(float s) {
  return fast_rcp(1.f + __builtin_amdgcn_exp2f(s));
}
static __device__ __forceinline__ float tanh_pre(float s) {
  return __builtin_fmaf(2.f, fast_rcp(1.f + __builtin_amdgcn_exp2f(s)), -1.f);
}
static __device__ __forceinline__ float tanh_f(float x) {
  return __builtin_fmaf(2.f, fast_rcp(1.f + __builtin_amdgcn_exp2f(-2.88539008f * x)), -1.f);
}
static __device__ __forceinline__ float bf2f(__hip_bfloat16 v) { return __bfloat162float(v); }
static __device__ __forceinline__ short f2bs(float f) {
  __hip_bfloat16 h = __float2bfloat16(f);
  return *reinterpret_cast<short*>(&h);
}
// LDS-only barrier: skip the vmcnt(0) drain __syncthreads would force.
static __device__ __forceinline__ void barrier_lgkm() {
  asm volatile("s_waitcnt lgkmcnt(0)\n\ts_barrier" ::: "memory");
}

// ---------------------------------------------------------------------------
// R21 = R19 (verified best, R=16, 64 blocks, ~265us kernel) + 3 critical-path
// trims. R20 evidence (R=8, step time UNCHANGED): wave-wide issue is
// exec-mask-invariant and per-block LDS traffic is row-count-invariant ->
// step is pinned by the LDS latency chain + barrier sync. Trims:
//  1. id prefetch (idn reg): removes the 120cy id_s hop from the t+1 gather
//     chain (id -> addr -> Ea/eps read -> MFMA) between S2 and the barrier.
//  2. kc=0 peeled h-MFMAs seed C-in from persistent bn2v/byv frags: deletes
//     per-step anh/agl init movs.
//  3. input-MFMAs take gxc[g] directly as C-in.
// RB=16 geometry byte-identical to R19 otherwise.
// ---------------------------------------------------------------------------
__global__ __launch_bounds__(512, 2) void gru_kernel(
    const float* __restrict__ x,     // [B,64]
    const int* __restrict__ a_ids,   // [B,T]
    const int* __restrict__ t_ids,   // [B,T]
    const float* __restrict__ y,     // [B,T]
    const float* __restrict__ eps,   // [B,T,16]
    const float* __restrict__ Wx,    // [64,64]
    const float* __restrict__ bx,    // [64]
    const float* __restrict__ Ea,    // [100,32]
    const float* __restrict__ Et,    // [4,16]
    const float* __restrict__ Wih,   // [384,129]
    const float* __restrict__ Whh,   // [384,128]
    const float* __restrict__ bih,   // [384]
    const float* __restrict__ bhh,   // [384]
    const float* __restrict__ W0,    // [128,80]
    const float* __restrict__ b0g,   // [128]
    const float* __restrict__ Wy,    // [1,128]
    const float* __restrict__ by,    // [1]
    float* __restrict__ out)         // [B,T,2]
{
  // ---- persistent LDS ----
  __shared__ __align__(16) __hip_bfloat16 h_bf[2][16][136];  // h mirror (h_bf[1] = xdyn in prologue)
  __shared__ __align__(16) __hip_bfloat16 Ea_s[100][40];     // padded rows (data in cols 0..31)
  __shared__ __align__(16) __hip_bfloat16 Et_s[4][16];
  __shared__ float prevy_s[2][16];
  __shared__ float bsum_r[128], bsum_z[128], bihn_s[128], bhhn_s[128];  // pre-scaled
  __shared__ float wprev_s[384];                                        // pre-scaled
  // ---- unioned region (38912 B) ----
  // persistent: id_s[256][16]u16 @0 | eps_ch[2][16][16][24]bf16 @8192
  //             y_ch[2][16][16]f32 @32768
  // prologue:   Wxb[64][64]bf16 @0 | W0b[128][80]bf16 @8192 | x_s[16][65]f32 @28672
  //             eps0s[16][17]f32 @32832 | xe_s[16][65]f32 @33920 | h0f[16][128]f32 @0
  __shared__ __align__(16) char uni[38912];
  unsigned short* id_s    = (unsigned short*)(uni);
  __hip_bfloat16* eps_ch  = (__hip_bfloat16*)(uni + 8192);
  float*          y_ch    = (float*)(uni + 32768);
  __hip_bfloat16* Wxb     = (__hip_bfloat16*)(uni);
  __hip_bfloat16* W0b     = (__hip_bfloat16*)(uni + 8192);
  float*          x_s     = (float*)(uni + 28672);
  float*          eps0s   = (float*)(uni + 32832);
  float*          xe_s    = (float*)(uni + 33920);
  float*          h0f     = (float*)(uni);

  const int tid = threadIdx.x;
  const int w = tid >> 6, l = tid & 63;
  const int lmod = l & 15, ldiv = l >> 4;
  const int i_own = 16 * w + lmod;
  const int b0 = blockIdx.x * 16;

  // ================= PROLOGUE =================
  if (tid < 128) {
    bsum_r[tid] = KSIG * (bih[tid] + bhh[tid]);
    bsum_z[tid] = KSIG * (bih[128 + tid] + bhh[128 + tid]);
    bihn_s[tid] = KTAN * bih[256 + tid];
    bhhn_s[tid] = KTAN * bhh[256 + tid];
  }
  if (tid < 384) wprev_s[tid] = ((tid < 256) ? KSIG : KTAN) * Wih[tid * 129 + 128];
  for (int j = tid; j < 3200; j += 512) {
    int r = j >> 5, c = j & 31;
    Ea_s[r][c] = __float2bfloat16(Ea[j]);
  }
  if (tid < 64) ((__hip_bfloat16*)Et_s)[tid] = __float2bfloat16(Et[tid]);
  for (int j = tid; j < 4096; j += 512)  Wxb[j] = __float2bfloat16(Wx[j]);
  for (int j = tid; j < 10240; j += 512) W0b[j] = __float2bfloat16(W0[j]);
  for (int j = tid; j < 1024; j += 512) {
    int r = j >> 6, c = j & 63;
    x_s[r * 65 + c] = x[(b0 + r) * 64 + c];
  }
  if (tid < 256) {
    int r = tid >> 4, c = tid & 15;
    eps0s[r * 17 + c] = eps[((b0 + r) * NT) * 16 + c];
  }
  const float by_f = by[0];

  // persistent B-frags: wave w owns gate-cols i_own of r/z/n. Pre-scaled.
  bfrag Bh[3][4], Bi[3][2];
  #pragma unroll
  for (int g = 0; g < 3; g++) {
    const float sg = (g < 2) ? KSIG : KTAN;
    int n = (g * 8 + w) * 16 + lmod;
    #pragma unroll
    for (int kc = 0; kc < 4; kc++) {
      int k = kc * 32 + ldiv * 8;
      const float* wh = Whh + n * 128 + k;
      float4 h0v = *reinterpret_cast<const float4*>(wh);
      float4 h1v = *reinterpret_cast<const float4*>(wh + 4);
      bfrag th = {f2bs(sg * h0v.x), f2bs(sg * h0v.y), f2bs(sg * h0v.z), f2bs(sg * h0v.w),
                  f2bs(sg * h1v.x), f2bs(sg * h1v.y), f2bs(sg * h1v.z), f2bs(sg * h1v.w)};
      Bh[g][kc] = th;
    }
    #pragma unroll
    for (int kc = 0; kc < 2; kc++) {
      bfrag ti;
      #pragma unroll
      for (int j = 0; j < 8; j++) {
        int dk = kc * 32 + ldiv * 8 + j;
        int col = dk < 48 ? dk : dk + 64;
        ti[j] = f2bs(sg * Wih[n * 129 + col]);
      }
      Bi[g][kc] = ti;
    }
  }
  // logit B-tile for wave 7: col 0 = Wy, other cols 0 (UNscaled)
  bfrag Bl[4];
  if (w == 7) {
    #pragma unroll
    for (int kc = 0; kc < 4; kc++) {
      bfrag bt;
      #pragma unroll
      for (int j = 0; j < 8; j++)
        bt[j] = (lmod == 0) ? f2bs(Wy[kc * 32 + ldiv * 8 + j]) : (short)0;
      Bl[kc] = bt;
    }
  }
  __syncthreads();  // B1: x_s, Wxb, tables ready

  // ph1: xenc = x@Wx.T + bx -> xe_s (f32) + xdyn bf16 (in h_bf[1])
  for (int j = tid; j < 1024; j += 512) {
    int r = j & 15, i = j >> 4;
    float acc = bx[i];
    #pragma unroll 8
    for (int k = 0; k < 64; k++) acc += x_s[r * 65 + k] * bf2f(Wxb[i * 64 + k]);
    xe_s[r * 65 + i] = acc;
    h_bf[1][r][i] = __float2bfloat16(acc);
  }
  __syncthreads();  // B2: xe_s + xdyn ready; Wxb dead

  // ph2: h0 = tanh([xenc,eps0]@W0.T + b0) -> h0f (overwrites Wxb region)
  for (int j = tid; j < 2048; j += 512) {
    int r = j & 15, o = j >> 4;
    float acc = b0g[o];
    #pragma unroll 8
    for (int k = 0; k < 64; k++) acc += xe_s[r * 65 + k] * bf2f(W0b[o * 80 + k]);
    #pragma unroll
    for (int k = 0; k < 16; k++) acc += eps0s[r * 17 + k] * bf2f(W0b[o * 80 + 64 + k]);
    h0f[r * 128 + o] = tanh_f(acc);
  }

  // gxc = scaled( xenc @ Wih[:,48:112].T + per-gate biases )
  ffrag gxc[3];
  {
    ffrag z = {0.f, 0.f, 0.f, 0.f};
    gxc[0] = z; gxc[1] = z; gxc[2] = z;
    #pragma unroll
    for (int kc = 0; kc < 2; kc++) {
      bfrag axd = *reinterpret_cast<const bfrag*>(&h_bf[1][lmod][kc * 32 + ldiv * 8]);
      #pragma unroll
      for (int g = 0; g < 3; g++) {
        const float sg = (g < 2) ? KSIG : KTAN;
        int n = (g * 8 + w) * 16 + lmod;
        const float* wi = Wih + n * 129 + 48 + kc * 32 + ldiv * 8;
        bfrag bt;
        #pragma unroll
        for (int j = 0; j < 8; j++) bt[j] = f2bs(sg * wi[j]);
        gxc[g] = __builtin_amdgcn_mfma_f32_16x16x32_bf16(axd, bt, gxc[g], 0, 0, 0);
      }
    }
    float brf = bsum_r[i_own], bzf = bsum_z[i_own], bn1 = bihn_s[i_own];
    #pragma unroll
    for (int q = 0; q < 4; q++) {
      gxc[0][q] += brf;
      gxc[1][q] += bzf;
      gxc[2][q] += bn1;
    }
  }
  __syncthreads();  // B3: h0f complete; gxc done

  // h init: fp32 regs + bf16 mirror in h_bf[0]
  float h_reg[4];
  #pragma unroll
  for (int q = 0; q < 4; q++) {
    int row = ldiv * 4 + q;
    float hv = h0f[row * 128 + i_own];
    h_reg[q] = hv;
    h_bf[0][row][i_own] = __float2bfloat16(hv);
  }
  __syncthreads();  // B4: h0f dead; uni becomes persistent

  // ids (packed, [t][row]) + chunk 0 of eps/y
  for (int j = tid; j < 4096; j += 512) {
    int r = j >> 8, t = j & 255;
    unsigned short v = (unsigned short)(a_ids[(b0 + r) * NT + t] |
                                        (t_ids[(b0 + r) * NT + t] << 8));
    id_s[t * 16 + r] = v;
  }
  {
    int r = tid >> 5, sub = tid & 31;
    const float* p = eps + ((b0 + r) * NT) * 16 + sub * 8;
    float4 eA = *reinterpret_cast<const float4*>(p);
    float4 eB = *reinterpret_cast<const float4*>(p + 4);
    int toff = sub >> 1, c8 = (sub & 1) * 8;
    bfrag e = {f2bs(eA.x), f2bs(eA.y), f2bs(eA.z), f2bs(eA.w),
               f2bs(eB.x), f2bs(eB.y), f2bs(eB.z), f2bs(eB.w)};
    *reinterpret_cast<bfrag*>(&eps_ch[(toff * 16 + r) * 24 + c8]) = e;
    if (tid < 64) {
      int r2 = tid >> 2, s2 = tid & 3;
      float4 yv = *reinterpret_cast<const float4*>(y + (b0 + r2) * NT + s2 * 4);
      *reinterpret_cast<float4*>(&y_ch[r2 * 16 + s2 * 4]) = yv;
    }
  }
  if (tid < 16) prevy_s[0][tid] = 0.f;
  // hoisted per-lane constants (pre-scaled)
  const float wpr = wprev_s[i_own], wpz = wprev_s[128 + i_own], wpn = wprev_s[256 + i_own];
  const float bn2 = bhhn_s[i_own];
  // persistent seed frags: C-in for the peeled kc=0 MFMAs (no per-step movs)
  ffrag bn2v, byv;
  #pragma unroll
  for (int q = 0; q < 4; q++) { bn2v[q] = bn2; byv[q] = by_f; }
  // hoisted per-lane address pieces for the direct dyn-input gather
  const char* const ea_base  = (const char*)Ea_s + ldiv * 16;
  const char* const et_base  = (const char*)Et_s + ldiv * 16;
  const char* const eps_base = (const char*)eps_ch + lmod * 48 + (ldiv - 2) * 16;
  __syncthreads();  // B5: id_s / eps_ch chunk0 / y_ch ready

  // input-gate MFMAs for t=0
  ffrag pa0, pa1, pa2;
  {
    int id = id_s[lmod];
    int aid = id & 127, tv = id >> 8;
    bfrag axA = *reinterpret_cast<const bfrag*>(ea_base + aid * 80);
    const char* etp = et_base + tv * 32;
    const char* epp = eps_base;  // t=0: cbn=0, tm=0
    bfrag axB = *reinterpret_cast<const bfrag*>(ldiv < 2 ? etp : epp);
    pa0 = __builtin_amdgcn_mfma_f32_16x16x32_bf16(axA, Bi[0][0], gxc[0], 0, 0, 0);
    pa1 = __builtin_amdgcn_mfma_f32_16x16x32_bf16(axA, Bi[1][0], gxc[1], 0, 0, 0);
    pa2 = __builtin_amdgcn_mfma_f32_16x16x32_bf16(axA, Bi[2][0], gxc[2], 0, 0, 0);
    pa0 = __builtin_amdgcn_mfma_f32_16x16x32_bf16(axB, Bi[0][1], pa0, 0, 0, 0);
    pa1 = __builtin_amdgcn_mfma_f32_16x16x32_bf16(axB, Bi[1][1], pa1, 0, 0, 0);
    pa2 = __builtin_amdgcn_mfma_f32_16x16x32_bf16(axB, Bi[2][1], pa2, 0, 0, 0);
  }
  // id prefetch: idn holds the packed id for step t+1's gather
  int idn = id_s[16 + lmod];

  // ================= MAIN LOOP =================
  for (int t = 0; t < NT; t++) {
    const int buf = t & 1, nbuf = buf ^ 1;

    // consume prefetched id; issue prefetch for t+2 (whole step to land)
    const int id_cur = idn;
    if (t + 2 < NT) idn = id_s[(t + 2) * 16 + lmod];

    // issue next-chunk global loads (rare)
    const bool ck = ((t & 15) == 0) && (t + 16 < NT);
    float4 eA, eB, yv;
    const int cr = tid >> 5, csub = tid & 31;
    if (ck) {
      const float* p = eps + ((b0 + cr) * NT + t + 16) * 16 + csub * 8;
      eA = *reinterpret_cast<const float4*>(p);
      eB = *reinterpret_cast<const float4*>(p + 4);
      if (tid < 64) {
        int r2 = tid >> 2, s2 = tid & 3;
        yv = *reinterpret_cast<const float4*>(y + (b0 + r2) * NT + t + 16 + s2 * 4);
      }
    }

    // h-MFMAs: kc=0 peeled with seed-frag C-in (no anh/agl init movs)
    ffrag anh, agl;
    {
      bfrag ah0 = *reinterpret_cast<const bfrag*>(&h_bf[buf][lmod][ldiv * 8]);
      pa0 = __builtin_amdgcn_mfma_f32_16x16x32_bf16(ah0, Bh[0][0], pa0, 0, 0, 0);
      pa1 = __builtin_amdgcn_mfma_f32_16x16x32_bf16(ah0, Bh[1][0], pa1, 0, 0, 0);
      anh = __builtin_amdgcn_mfma_f32_16x16x32_bf16(ah0, Bh[2][0], bn2v, 0, 0, 0);
      if (w == 7)
        agl = __builtin_amdgcn_mfma_f32_16x16x32_bf16(ah0, Bl[0], byv, 0, 0, 0);
    }
    #pragma unroll
    for (int kc = 1; kc < 4; kc++) {
      bfrag ah = *reinterpret_cast<const bfrag*>(&h_bf[buf][lmod][kc * 32 + ldiv * 8]);
      pa0 = __builtin_amdgcn_mfma_f32_16x16x32_bf16(ah, Bh[0][kc], pa0, 0, 0, 0);
      pa1 = __builtin_amdgcn_mfma_f32_16x16x32_bf16(ah, Bh[1][kc], pa1, 0, 0, 0);
      anh = __builtin_amdgcn_mfma_f32_16x16x32_bf16(ah, Bh[2][kc], anh, 0, 0, 0);
      if (w == 7)
        agl = __builtin_amdgcn_mfma_f32_16x16x32_bf16(ah, Bl[kc], agl, 0, 0, 0);
    }

    // prevy for t+1 (wave 6)
    if (tid >= 384 && tid < 400) {
      int r = tid - 384;
      prevy_s[nbuf][r] = y_ch[((t >> 4) & 1) * 256 + r * 16 + (t & 15)];
    }

    // wave 7: logit/prob for step t-1 -> DIRECT global float2 stores
    if (w == 7 && t > 0 && lmod == 0) {
      #pragma unroll
      for (int q = 0; q < 4; q++) {
        int row = ldiv * 4 + q;
        float lg = agl[q];
        float2 v;
        v.x = lg;
        v.y = sigm(lg);
        *reinterpret_cast<float2*>(out + ((b0 + row) * NT + (t - 1)) * 2) = v;
      }
    }

    // S2: gates, h update (args pre-scaled; no per-activation mul)
    #pragma unroll
    for (int q = 0; q < 4; q++) {
      int row = ldiv * 4 + q;
      float py = prevy_s[buf][row];
      float rv = sigm_pre(__builtin_fmaf(py, wpr, pa0[q]));
      float zv = sigm_pre(__builtin_fmaf(py, wpz, pa1[q]));
      float nv = tanh_pre(__builtin_fmaf(rv, anh[q], __builtin_fmaf(py, wpn, pa2[q])));
      float hn = __builtin_fmaf(zv, h_reg[q] - nv, nv);
      h_reg[q] = hn;
      h_bf[nbuf][row][i_own] = __float2bfloat16(hn);
    }

    // input-gate MFMAs for t+1 (uses prefetched id; hides under barrier)
    if (t + 1 < NT) {
      const int tn = t + 1;
      const int ebase = (((tn >> 4) & 1) * 16 + (tn & 15)) * 16;  // eps row-block
      int aid = id_cur & 127, tv = id_cur >> 8;
      bfrag axA = *reinterpret_cast<const bfrag*>(ea_base + aid * 80);
      const char* etp = et_base + tv * 32;
      const char* epp = eps_base + ebase * 48;
      bfrag axB = *reinterpret_cast<const bfrag*>(ldiv < 2 ? etp : epp);
      pa0 = __builtin_amdgcn_mfma_f32_16x16x32_bf16(axA, Bi[0][0], gxc[0], 0, 0, 0);
      pa1 = __builtin_amdgcn_mfma_f32_16x16x32_bf16(axA, Bi[1][0], gxc[1], 0, 0, 0);
      pa2 = __builtin_amdgcn_mfma_f32_16x16x32_bf16(axA, Bi[2][0], gxc[2], 0, 0, 0);
      pa0 = __builtin_amdgcn_mfma_f32_16x16x32_bf16(axB, Bi[0][1], pa0, 0, 0, 0);
      pa1 = __builtin_amdgcn_mfma_f32_16x16x32_bf16(axB, Bi[1][1], pa1, 0, 0, 0);
      pa2 = __builtin_amdgcn_mfma_f32_16x16x32_bf16(axB, Bi[2][1], pa2, 0, 0, 0);
    }

    // next-chunk convert + LDS write (rare)
    if (ck) {
      int cb2 = ((t >> 4) + 1) & 1;
      int toff = csub >> 1, c8 = (csub & 1) * 8;
      bfrag e = {f2bs(eA.x), f2bs(eA.y), f2bs(eA.z), f2bs(eA.w),
                 f2bs(eB.x), f2bs(eB.y), f2bs(eB.z), f2bs(eB.w)};
      *reinterpret_cast<bfrag*>(&eps_ch[((cb2 * 16 + toff) * 16 + cr) * 24 + c8]) = e;
      if (tid < 64) {
        int r2 = tid >> 2, s2 = tid & 3;
        *reinterpret_cast<float4*>(&y_ch[cb2 * 256 + r2 * 16 + s2 * 4]) = yv;
      }
    }

    barrier_lgkm();  // the ONE barrier per step (LDS-only drain)
  }

  // ---- tail: logit for step 255 from h_bf[0] (= H_256), direct store ----
  if (w == 7) {
    ffrag agl;
    {
      bfrag ah0 = *reinterpret_cast<const bfrag*>(&h_bf[0][lmod][ldiv * 8]);
      agl = __builtin_amdgcn_mfma_f32_16x16x32_bf16(ah0, Bl[0], byv, 0, 0, 0);
    }
    #pragma unroll
    for (int kc = 1; kc < 4; kc++) {
      bfrag ah = *reinterpret_cast<const bfrag*>(&h_bf[0][lmod][kc * 32 + ldiv * 8]);
      agl = __builtin_amdgcn_mfma_f32_16x16x32_bf16(ah, Bl[kc], agl, 0, 0, 0);
    }
    if (lmod == 0) {
      #pragma unroll
      for (int q = 0; q < 4; q++) {
        int row = ldiv * 4 + q;
        float lg = agl[q];
        float2 v;
        v.x = lg;
        v.y = sigm(lg);
        *reinterpret_cast<float2*>(out + ((b0 + row) * NT + 255) * 2) = v;
      }
    }
  }
}

extern "C" void kernel_launch(void* const* d_in, const int* in_sizes, int n_in,
                              void* d_out, int out_size, void* d_ws, size_t ws_size,
                              hipStream_t stream) {
  const float* x   = (const float*)d_in[0];
  const int*   a   = (const int*)d_in[1];
  const int*   tt  = (const int*)d_in[2];
  const float* y   = (const float*)d_in[3];
  // d_in[4] = mask: forward output is mask-independent (m*v + (1-m)*v == v)
  const float* eps = (const float*)d_in[5];
  const float* Wx  = (const float*)d_in[6];
  const float* bx  = (const float*)d_in[7];
  const float* Ea  = (const float*)d_in[8];
  const float* Et  = (const float*)d_in[9];
  const float* Wih = (const float*)d_in[10];
  const float* Whh = (const float*)d_in[11];
  const float* bih = (const float*)d_in[12];
  const float* bhh = (const float*)d_in[13];
  const float* W0  = (const float*)d_in[14];
  const float* b0  = (const float*)d_in[15];
  const float* Wy  = (const float*)d_in[16];
  const float* by  = (const float*)d_in[17];
  float* out = (float*)d_out;

  gru_kernel<<<NB / 16, 512, 0, stream>>>(x, a, tt, y, eps, Wx, bx, Ea, Et,
                                          Wih, Whh, bih, bhh, W0, b0, Wy, by, out);
}

// Round 11
// 342.685 us; speedup vs baseline: 1.0374x; 1.0117x over previous
//
#include <hip/hip_runtime.h>
#include <hip/hip_bf16.h>

typedef __attribute__((ext_vector_type(8))) short bfrag;   // 8 x bf16 (4 VGPRs)
typedef __attribute__((ext_vector_type(4))) float ffrag;   // 4 x f32 acc

#define NB 1024
#define NT 256

// -log2(e), -2*log2(e): folded into weights so S2 needs no per-activation mul.
#define KSIG -1.44269504f
#define KTAN -2.88539008f

static __device__ __forceinline__ float fast_rcp(float x) { return __builtin_amdgcn_rcpf(x); }
// unscaled (logit path only)
static __device__ __forceinline__ float sigm(float x) {
  return fast_rcp(1.f + __builtin_amdgcn_exp2f(-1.44269504f * x));
}
// pre-scaled args (weights already multiplied by KSIG/KTAN)
static __device__ __forceinline__ float sigm_pre(float s) {
  return fast_rcp(1.f + __builtin_amdgcn_exp2f(s));
}
static __device__ __forceinline__ float tanh_pre(float s) {
  return __builtin_fmaf(2.f, fast_rcp(1.f + __builtin_amdgcn_exp2f(s)), -1.f);
}
static __device__ __forceinline__ float tanh_f(float x) {
  return __builtin_fmaf(2.f, fast_rcp(1.f + __builtin_amdgcn_exp2f(-2.88539008f * x)), -1.f);
}
static __device__ __forceinline__ float bf2f(__hip_bfloat16 v) { return __bfloat162float(v); }
static __device__ __forceinline__ short f2bs(float f) {
  __hip_bfloat16 h = __float2bfloat16(f);
  return *reinterpret_cast<short*>(&h);
}
// LDS-only barrier: skip the vmcnt(0) drain __syncthreads would force.
static __device__ __forceinline__ void barrier_lgkm() {
  asm volatile("s_waitcnt lgkmcnt(0)\n\ts_barrier" ::: "memory");
}

// ---------------------------------------------------------------------------
// R22 = R21 (verified best, 257.5us kernel) + unroll-2 accumulator rotation.
// R21 counters: MFMA issue 660cy (floor), VALU 1070cy, ~700cy exposed stall.
// The t+1 input-gather chain (ds_read + 6 MFMA, ~240cy latency) sat AFTER S2
// right before the barrier — fully exposed — because it overwrites the same
// pa0-2 regs S2 reads. Unroll x2 with pA/pB sets breaks the false dep: each
// half-step issues {h-MFMA(cur) -> input-MFMA(next, other set) -> S2(cur)},
// letting the gather+MFMA latency hide under S2's ~200cy trans work.
// (NOT R17's failed hoist: gather reads stay after the h A-frag reads.)
// Also: prevy read vectorized to one ds_read_b128 (was 4x b32).
// ---------------------------------------------------------------------------
__global__ __launch_bounds__(512, 2) void gru_kernel(
    const float* __restrict__ x,     // [B,64]
    const int* __restrict__ a_ids,   // [B,T]
    const int* __restrict__ t_ids,   // [B,T]
    const float* __restrict__ y,     // [B,T]
    const float* __restrict__ eps,   // [B,T,16]
    const float* __restrict__ Wx,    // [64,64]
    const float* __restrict__ bx,    // [64]
    const float* __restrict__ Ea,    // [100,32]
    const float* __restrict__ Et,    // [4,16]
    const float* __restrict__ Wih,   // [384,129]
    const float* __restrict__ Whh,   // [384,128]
    const float* __restrict__ bih,   // [384]
    const float* __restrict__ bhh,   // [384]
    const float* __restrict__ W0,    // [128,80]
    const float* __restrict__ b0g,   // [128]
    const float* __restrict__ Wy,    // [1,128]
    const float* __restrict__ by,    // [1]
    float* __restrict__ out)         // [B,T,2]
{
  // ---- persistent LDS ----
  __shared__ __align__(16) __hip_bfloat16 h_bf[2][16][136];  // h mirror (h_bf[1] = xdyn in prologue)
  __shared__ __align__(16) __hip_bfloat16 Ea_s[100][40];     // padded rows (data in cols 0..31)
  __shared__ __align__(16) __hip_bfloat16 Et_s[4][16];
  __shared__ __align__(16) float prevy_s[2][16];
  __shared__ float bsum_r[128], bsum_z[128], bihn_s[128], bhhn_s[128];  // pre-scaled
  __shared__ float wprev_s[384];                                        // pre-scaled
  // ---- unioned region (38912 B) ----
  // persistent: id_s[256][16]u16 @0 | eps_ch[2][16][16][24]bf16 @8192
  //             y_ch[2][16][16]f32 @32768
  // prologue:   Wxb[64][64]bf16 @0 | W0b[128][80]bf16 @8192 | x_s[16][65]f32 @28672
  //             eps0s[16][17]f32 @32832 | xe_s[16][65]f32 @33920 | h0f[16][128]f32 @0
  __shared__ __align__(16) char uni[38912];
  unsigned short* id_s    = (unsigned short*)(uni);
  __hip_bfloat16* eps_ch  = (__hip_bfloat16*)(uni + 8192);
  float*          y_ch    = (float*)(uni + 32768);
  __hip_bfloat16* Wxb     = (__hip_bfloat16*)(uni);
  __hip_bfloat16* W0b     = (__hip_bfloat16*)(uni + 8192);
  float*          x_s     = (float*)(uni + 28672);
  float*          eps0s   = (float*)(uni + 32832);
  float*          xe_s    = (float*)(uni + 33920);
  float*          h0f     = (float*)(uni);

  const int tid = threadIdx.x;
  const int w = tid >> 6, l = tid & 63;
  const int lmod = l & 15, ldiv = l >> 4;
  const int i_own = 16 * w + lmod;
  const int b0 = blockIdx.x * 16;

  // ================= PROLOGUE =================
  if (tid < 128) {
    bsum_r[tid] = KSIG * (bih[tid] + bhh[tid]);
    bsum_z[tid] = KSIG * (bih[128 + tid] + bhh[128 + tid]);
    bihn_s[tid] = KTAN * bih[256 + tid];
    bhhn_s[tid] = KTAN * bhh[256 + tid];
  }
  if (tid < 384) wprev_s[tid] = ((tid < 256) ? KSIG : KTAN) * Wih[tid * 129 + 128];
  for (int j = tid; j < 3200; j += 512) {
    int r = j >> 5, c = j & 31;
    Ea_s[r][c] = __float2bfloat16(Ea[j]);
  }
  if (tid < 64) ((__hip_bfloat16*)Et_s)[tid] = __float2bfloat16(Et[tid]);
  for (int j = tid; j < 4096; j += 512)  Wxb[j] = __float2bfloat16(Wx[j]);
  for (int j = tid; j < 10240; j += 512) W0b[j] = __float2bfloat16(W0[j]);
  for (int j = tid; j < 1024; j += 512) {
    int r = j >> 6, c = j & 63;
    x_s[r * 65 + c] = x[(b0 + r) * 64 + c];
  }
  if (tid < 256) {
    int r = tid >> 4, c = tid & 15;
    eps0s[r * 17 + c] = eps[((b0 + r) * NT) * 16 + c];
  }
  const float by_f = by[0];

  // persistent B-frags: wave w owns gate-cols i_own of r/z/n. Pre-scaled.
  bfrag Bh[3][4], Bi[3][2];
  #pragma unroll
  for (int g = 0; g < 3; g++) {
    const float sg = (g < 2) ? KSIG : KTAN;
    int n = (g * 8 + w) * 16 + lmod;
    #pragma unroll
    for (int kc = 0; kc < 4; kc++) {
      int k = kc * 32 + ldiv * 8;
      const float* wh = Whh + n * 128 + k;
      float4 h0v = *reinterpret_cast<const float4*>(wh);
      float4 h1v = *reinterpret_cast<const float4*>(wh + 4);
      bfrag th = {f2bs(sg * h0v.x), f2bs(sg * h0v.y), f2bs(sg * h0v.z), f2bs(sg * h0v.w),
                  f2bs(sg * h1v.x), f2bs(sg * h1v.y), f2bs(sg * h1v.z), f2bs(sg * h1v.w)};
      Bh[g][kc] = th;
    }
    #pragma unroll
    for (int kc = 0; kc < 2; kc++) {
      bfrag ti;
      #pragma unroll
      for (int j = 0; j < 8; j++) {
        int dk = kc * 32 + ldiv * 8 + j;
        int col = dk < 48 ? dk : dk + 64;
        ti[j] = f2bs(sg * Wih[n * 129 + col]);
      }
      Bi[g][kc] = ti;
    }
  }
  // logit B-tile for wave 7: col 0 = Wy, other cols 0 (UNscaled)
  bfrag Bl[4];
  if (w == 7) {
    #pragma unroll
    for (int kc = 0; kc < 4; kc++) {
      bfrag bt;
      #pragma unroll
      for (int j = 0; j < 8; j++)
        bt[j] = (lmod == 0) ? f2bs(Wy[kc * 32 + ldiv * 8 + j]) : (short)0;
      Bl[kc] = bt;
    }
  }
  __syncthreads();  // B1: x_s, Wxb, tables ready

  // ph1: xenc = x@Wx.T + bx -> xe_s (f32) + xdyn bf16 (in h_bf[1])
  for (int j = tid; j < 1024; j += 512) {
    int r = j & 15, i = j >> 4;
    float acc = bx[i];
    #pragma unroll 8
    for (int k = 0; k < 64; k++) acc += x_s[r * 65 + k] * bf2f(Wxb[i * 64 + k]);
    xe_s[r * 65 + i] = acc;
    h_bf[1][r][i] = __float2bfloat16(acc);
  }
  __syncthreads();  // B2: xe_s + xdyn ready; Wxb dead

  // ph2: h0 = tanh([xenc,eps0]@W0.T + b0) -> h0f (overwrites Wxb region)
  for (int j = tid; j < 2048; j += 512) {
    int r = j & 15, o = j >> 4;
    float acc = b0g[o];
    #pragma unroll 8
    for (int k = 0; k < 64; k++) acc += xe_s[r * 65 + k] * bf2f(W0b[o * 80 + k]);
    #pragma unroll
    for (int k = 0; k < 16; k++) acc += eps0s[r * 17 + k] * bf2f(W0b[o * 80 + 64 + k]);
    h0f[r * 128 + o] = tanh_f(acc);
  }

  // gxc = scaled( xenc @ Wih[:,48:112].T + per-gate biases )
  ffrag gxc[3];
  {
    ffrag z = {0.f, 0.f, 0.f, 0.f};
    gxc[0] = z; gxc[1] = z; gxc[2] = z;
    #pragma unroll
    for (int kc = 0; kc < 2; kc++) {
      bfrag axd = *reinterpret_cast<const bfrag*>(&h_bf[1][lmod][kc * 32 + ldiv * 8]);
      #pragma unroll
      for (int g = 0; g < 3; g++) {
        const float sg = (g < 2) ? KSIG : KTAN;
        int n = (g * 8 + w) * 16 + lmod;
        const float* wi = Wih + n * 129 + 48 + kc * 32 + ldiv * 8;
        bfrag bt;
        #pragma unroll
        for (int j = 0; j < 8; j++) bt[j] = f2bs(sg * wi[j]);
        gxc[g] = __builtin_amdgcn_mfma_f32_16x16x32_bf16(axd, bt, gxc[g], 0, 0, 0);
      }
    }
    float brf = bsum_r[i_own], bzf = bsum_z[i_own], bn1 = bihn_s[i_own];
    #pragma unroll
    for (int q = 0; q < 4; q++) {
      gxc[0][q] += brf;
      gxc[1][q] += bzf;
      gxc[2][q] += bn1;
    }
  }
  __syncthreads();  // B3: h0f complete; gxc done

  // h init: fp32 regs + bf16 mirror in h_bf[0]
  float h_reg[4];
  #pragma unroll
  for (int q = 0; q < 4; q++) {
    int row = ldiv * 4 + q;
    float hv = h0f[row * 128 + i_own];
    h_reg[q] = hv;
    h_bf[0][row][i_own] = __float2bfloat16(hv);
  }
  __syncthreads();  // B4: h0f dead; uni becomes persistent

  // ids (packed, [t][row]) + chunk 0 of eps/y
  for (int j = tid; j < 4096; j += 512) {
    int r = j >> 8, t = j & 255;
    unsigned short v = (unsigned short)(a_ids[(b0 + r) * NT + t] |
                                        (t_ids[(b0 + r) * NT + t] << 8));
    id_s[t * 16 + r] = v;
  }
  {
    int r = tid >> 5, sub = tid & 31;
    const float* p = eps + ((b0 + r) * NT) * 16 + sub * 8;
    float4 eA = *reinterpret_cast<const float4*>(p);
    float4 eB = *reinterpret_cast<const float4*>(p + 4);
    int toff = sub >> 1, c8 = (sub & 1) * 8;
    bfrag e = {f2bs(eA.x), f2bs(eA.y), f2bs(eA.z), f2bs(eA.w),
               f2bs(eB.x), f2bs(eB.y), f2bs(eB.z), f2bs(eB.w)};
    *reinterpret_cast<bfrag*>(&eps_ch[(toff * 16 + r) * 24 + c8]) = e;
    if (tid < 64) {
      int r2 = tid >> 2, s2 = tid & 3;
      float4 yv = *reinterpret_cast<const float4*>(y + (b0 + r2) * NT + s2 * 4);
      *reinterpret_cast<float4*>(&y_ch[r2 * 16 + s2 * 4]) = yv;
    }
  }
  if (tid < 16) prevy_s[0][tid] = 0.f;
  // hoisted per-lane constants (pre-scaled)
  const float wpr = wprev_s[i_own], wpz = wprev_s[128 + i_own], wpn = wprev_s[256 + i_own];
  const float bn2 = bhhn_s[i_own];
  // persistent seed frags: C-in for the peeled kc=0 MFMAs (no per-step movs)
  ffrag bn2v, byv;
  #pragma unroll
  for (int q = 0; q < 4; q++) { bn2v[q] = bn2; byv[q] = by_f; }
  // hoisted per-lane address pieces for the direct dyn-input gather
  const char* const ea_base  = (const char*)Ea_s + ldiv * 16;
  const char* const et_base  = (const char*)Et_s + ldiv * 16;
  const char* const eps_base = (const char*)eps_ch + lmod * 48 + (ldiv - 2) * 16;
  __syncthreads();  // B5: id_s / eps_ch chunk0 / y_ch ready

  // input-gate MFMAs for t=0 -> pA
  ffrag pA0, pA1, pA2, pB0, pB1, pB2;
  {
    int id = id_s[lmod];
    int aid = id & 127, tv = id >> 8;
    bfrag axA = *reinterpret_cast<const bfrag*>(ea_base + aid * 80);
    const char* etp = et_base + tv * 32;
    const char* epp = eps_base;  // t=0: cbn=0, tm=0
    bfrag axB = *reinterpret_cast<const bfrag*>(ldiv < 2 ? etp : epp);
    pA0 = __builtin_amdgcn_mfma_f32_16x16x32_bf16(axA, Bi[0][0], gxc[0], 0, 0, 0);
    pA1 = __builtin_amdgcn_mfma_f32_16x16x32_bf16(axA, Bi[1][0], gxc[1], 0, 0, 0);
    pA2 = __builtin_amdgcn_mfma_f32_16x16x32_bf16(axA, Bi[2][0], gxc[2], 0, 0, 0);
    pA0 = __builtin_amdgcn_mfma_f32_16x16x32_bf16(axB, Bi[0][1], pA0, 0, 0, 0);
    pA1 = __builtin_amdgcn_mfma_f32_16x16x32_bf16(axB, Bi[1][1], pA1, 0, 0, 0);
    pA2 = __builtin_amdgcn_mfma_f32_16x16x32_bf16(axB, Bi[2][1], pA2, 0, 0, 0);
  }
  // id prefetch: idn holds the packed id for the NEXT step's gather
  int idn = id_s[16 + lmod];

  // ================= MAIN LOOP (unroll x2, pA/pB rotation) =================
  for (int t = 0; t < NT; t += 2) {
    // ---------- half-step t (buf=0, nbuf=1): compute on pA, build pB ----------
    {
      const int id_cur = idn;
      if (t + 2 < NT) idn = id_s[(t + 2) * 16 + lmod];

      const bool ck = ((t & 15) == 0) && (t + 16 < NT);
      float4 eA, eB, yv;
      const int cr = tid >> 5, csub = tid & 31;
      if (ck) {
        const float* p = eps + ((b0 + cr) * NT + t + 16) * 16 + csub * 8;
        eA = *reinterpret_cast<const float4*>(p);
        eB = *reinterpret_cast<const float4*>(p + 4);
        if (tid < 64) {
          int r2 = tid >> 2, s2 = tid & 3;
          yv = *reinterpret_cast<const float4*>(y + (b0 + r2) * NT + t + 16 + s2 * 4);
        }
      }

      // h-MFMAs for step t (h_bf[0]); kc=0 peeled with seed-frag C-in
      ffrag anh, agl;
      {
        bfrag ah0 = *reinterpret_cast<const bfrag*>(&h_bf[0][lmod][ldiv * 8]);
        pA0 = __builtin_amdgcn_mfma_f32_16x16x32_bf16(ah0, Bh[0][0], pA0, 0, 0, 0);
        pA1 = __builtin_amdgcn_mfma_f32_16x16x32_bf16(ah0, Bh[1][0], pA1, 0, 0, 0);
        anh = __builtin_amdgcn_mfma_f32_16x16x32_bf16(ah0, Bh[2][0], bn2v, 0, 0, 0);
        if (w == 7)
          agl = __builtin_amdgcn_mfma_f32_16x16x32_bf16(ah0, Bl[0], byv, 0, 0, 0);
      }
      #pragma unroll
      for (int kc = 1; kc < 4; kc++) {
        bfrag ah = *reinterpret_cast<const bfrag*>(&h_bf[0][lmod][kc * 32 + ldiv * 8]);
        pA0 = __builtin_amdgcn_mfma_f32_16x16x32_bf16(ah, Bh[0][kc], pA0, 0, 0, 0);
        pA1 = __builtin_amdgcn_mfma_f32_16x16x32_bf16(ah, Bh[1][kc], pA1, 0, 0, 0);
        anh = __builtin_amdgcn_mfma_f32_16x16x32_bf16(ah, Bh[2][kc], anh, 0, 0, 0);
        if (w == 7)
          agl = __builtin_amdgcn_mfma_f32_16x16x32_bf16(ah, Bl[kc], agl, 0, 0, 0);
      }

      // input-gate MFMAs for t+1 -> pB (independent of S2's pA: overlaps trans)
      {
        const int tn = t + 1;
        const int ebase = (((tn >> 4) & 1) * 16 + (tn & 15)) * 16;
        int aid = id_cur & 127, tv = id_cur >> 8;
        bfrag axA = *reinterpret_cast<const bfrag*>(ea_base + aid * 80);
        const char* etp = et_base + tv * 32;
        const char* epp = eps_base + ebase * 48;
        bfrag axB = *reinterpret_cast<const bfrag*>(ldiv < 2 ? etp : epp);
        pB0 = __builtin_amdgcn_mfma_f32_16x16x32_bf16(axA, Bi[0][0], gxc[0], 0, 0, 0);
        pB1 = __builtin_amdgcn_mfma_f32_16x16x32_bf16(axA, Bi[1][0], gxc[1], 0, 0, 0);
        pB2 = __builtin_amdgcn_mfma_f32_16x16x32_bf16(axA, Bi[2][0], gxc[2], 0, 0, 0);
        pB0 = __builtin_amdgcn_mfma_f32_16x16x32_bf16(axB, Bi[0][1], pB0, 0, 0, 0);
        pB1 = __builtin_amdgcn_mfma_f32_16x16x32_bf16(axB, Bi[1][1], pB1, 0, 0, 0);
        pB2 = __builtin_amdgcn_mfma_f32_16x16x32_bf16(axB, Bi[2][1], pB2, 0, 0, 0);
      }

      // prevy for t+1 (wave 6)
      if (tid >= 384 && tid < 400) {
        int r = tid - 384;
        prevy_s[1][r] = y_ch[((t >> 4) & 1) * 256 + r * 16 + (t & 15)];
      }

      // wave 7: logit/prob for step t-1 -> DIRECT global float2 stores
      if (w == 7 && t > 0 && lmod == 0) {
        #pragma unroll
        for (int q = 0; q < 4; q++) {
          int row = ldiv * 4 + q;
          float lg = agl[q];
          float2 v;
          v.x = lg;
          v.y = sigm(lg);
          *reinterpret_cast<float2*>(out + ((b0 + row) * NT + (t - 1)) * 2) = v;
        }
      }

      // S2 on pA: gates, h update -> h_bf[1]
      {
        float4 pys = *reinterpret_cast<const float4*>(&prevy_s[0][ldiv * 4]);
        float pyv[4] = {pys.x, pys.y, pys.z, pys.w};
        #pragma unroll
        for (int q = 0; q < 4; q++) {
          int row = ldiv * 4 + q;
          float py = pyv[q];
          float rv = sigm_pre(__builtin_fmaf(py, wpr, pA0[q]));
          float zv = sigm_pre(__builtin_fmaf(py, wpz, pA1[q]));
          float nv = tanh_pre(__builtin_fmaf(rv, anh[q], __builtin_fmaf(py, wpn, pA2[q])));
          float hn = __builtin_fmaf(zv, h_reg[q] - nv, nv);
          h_reg[q] = hn;
          h_bf[1][row][i_own] = __float2bfloat16(hn);
        }
      }

      // next-chunk convert + LDS write (rare)
      if (ck) {
        int cb2 = ((t >> 4) + 1) & 1;
        int toff = csub >> 1, c8 = (csub & 1) * 8;
        bfrag e = {f2bs(eA.x), f2bs(eA.y), f2bs(eA.z), f2bs(eA.w),
                   f2bs(eB.x), f2bs(eB.y), f2bs(eB.z), f2bs(eB.w)};
        *reinterpret_cast<bfrag*>(&eps_ch[((cb2 * 16 + toff) * 16 + cr) * 24 + c8]) = e;
        if (tid < 64) {
          int r2 = tid >> 2, s2 = tid & 3;
          *reinterpret_cast<float4*>(&y_ch[cb2 * 256 + r2 * 16 + s2 * 4]) = yv;
        }
      }

      barrier_lgkm();
    }

    // ---------- half-step t+1 (buf=1, nbuf=0): compute on pB, build pA ----------
    {
      const int tc = t + 1;
      const int id_cur = idn;
      if (tc + 2 < NT) idn = id_s[(tc + 2) * 16 + lmod];

      // h-MFMAs for step tc (h_bf[1]); kc=0 peeled
      ffrag anh, agl;
      {
        bfrag ah0 = *reinterpret_cast<const bfrag*>(&h_bf[1][lmod][ldiv * 8]);
        pB0 = __builtin_amdgcn_mfma_f32_16x16x32_bf16(ah0, Bh[0][0], pB0, 0, 0, 0);
        pB1 = __builtin_amdgcn_mfma_f32_16x16x32_bf16(ah0, Bh[1][0], pB1, 0, 0, 0);
        anh = __builtin_amdgcn_mfma_f32_16x16x32_bf16(ah0, Bh[2][0], bn2v, 0, 0, 0);
        if (w == 7)
          agl = __builtin_amdgcn_mfma_f32_16x16x32_bf16(ah0, Bl[0], byv, 0, 0, 0);
      }
      #pragma unroll
      for (int kc = 1; kc < 4; kc++) {
        bfrag ah = *reinterpret_cast<const bfrag*>(&h_bf[1][lmod][kc * 32 + ldiv * 8]);
        pB0 = __builtin_amdgcn_mfma_f32_16x16x32_bf16(ah, Bh[0][kc], pB0, 0, 0, 0);
        pB1 = __builtin_amdgcn_mfma_f32_16x16x32_bf16(ah, Bh[1][kc], pB1, 0, 0, 0);
        anh = __builtin_amdgcn_mfma_f32_16x16x32_bf16(ah, Bh[2][kc], anh, 0, 0, 0);
        if (w == 7)
          agl = __builtin_amdgcn_mfma_f32_16x16x32_bf16(ah, Bl[kc], agl, 0, 0, 0);
      }

      // input-gate MFMAs for tc+1 -> pA (skip only at tc = NT-1)
      if (tc + 1 < NT) {
        const int tn = tc + 1;
        const int ebase = (((tn >> 4) & 1) * 16 + (tn & 15)) * 16;
        int aid = id_cur & 127, tv = id_cur >> 8;
        bfrag axA = *reinterpret_cast<const bfrag*>(ea_base + aid * 80);
        const char* etp = et_base + tv * 32;
        const char* epp = eps_base + ebase * 48;
        bfrag axB = *reinterpret_cast<const bfrag*>(ldiv < 2 ? etp : epp);
        pA0 = __builtin_amdgcn_mfma_f32_16x16x32_bf16(axA, Bi[0][0], gxc[0], 0, 0, 0);
        pA1 = __builtin_amdgcn_mfma_f32_16x16x32_bf16(axA, Bi[1][0], gxc[1], 0, 0, 0);
        pA2 = __builtin_amdgcn_mfma_f32_16x16x32_bf16(axA, Bi[2][0], gxc[2], 0, 0, 0);
        pA0 = __builtin_amdgcn_mfma_f32_16x16x32_bf16(axB, Bi[0][1], pA0, 0, 0, 0);
        pA1 = __builtin_amdgcn_mfma_f32_16x16x32_bf16(axB, Bi[1][1], pA1, 0, 0, 0);
        pA2 = __builtin_amdgcn_mfma_f32_16x16x32_bf16(axB, Bi[2][1], pA2, 0, 0, 0);
      }

      // prevy for tc+1 (wave 6)
      if (tid >= 384 && tid < 400) {
        int r = tid - 384;
        prevy_s[0][r] = y_ch[((tc >> 4) & 1) * 256 + r * 16 + (tc & 15)];
      }

      // wave 7: logit/prob for step tc-1 = t
      if (w == 7 && lmod == 0) {
        #pragma unroll
        for (int q = 0; q < 4; q++) {
          int row = ldiv * 4 + q;
          float lg = agl[q];
          float2 v;
          v.x = lg;
          v.y = sigm(lg);
          *reinterpret_cast<float2*>(out + ((b0 + row) * NT + (tc - 1)) * 2) = v;
        }
      }

      // S2 on pB: gates, h update -> h_bf[0]
      {
        float4 pys = *reinterpret_cast<const float4*>(&prevy_s[1][ldiv * 4]);
        float pyv[4] = {pys.x, pys.y, pys.z, pys.w};
        #pragma unroll
        for (int q = 0; q < 4; q++) {
          int row = ldiv * 4 + q;
          float py = pyv[q];
          float rv = sigm_pre(__builtin_fmaf(py, wpr, pB0[q]));
          float zv = sigm_pre(__builtin_fmaf(py, wpz, pB1[q]));
          float nv = tanh_pre(__builtin_fmaf(rv, anh[q], __builtin_fmaf(py, wpn, pB2[q])));
          float hn = __builtin_fmaf(zv, h_reg[q] - nv, nv);
          h_reg[q] = hn;
          h_bf[0][row][i_own] = __float2bfloat16(hn);
        }
      }

      barrier_lgkm();
    }
  }

  // ---- tail: logit for step 255 from h_bf[0] (= H_256), direct store ----
  if (w == 7) {
    ffrag agl;
    {
      bfrag ah0 = *reinterpret_cast<const bfrag*>(&h_bf[0][lmod][ldiv * 8]);
      agl = __builtin_amdgcn_mfma_f32_16x16x32_bf16(ah0, Bl[0], byv, 0, 0, 0);
    }
    #pragma unroll
    for (int kc = 1; kc < 4; kc++) {
      bfrag ah = *reinterpret_cast<const bfrag*>(&h_bf[0][lmod][kc * 32 + ldiv * 8]);
      agl = __builtin_amdgcn_mfma_f32_16x16x32_bf16(ah, Bl[kc], agl, 0, 0, 0);
    }
    if (lmod == 0) {
      #pragma unroll
      for (int q = 0; q < 4; q++) {
        int row = ldiv * 4 + q;
        float lg = agl[q];
        float2 v;
        v.x = lg;
        v.y = sigm(lg);
        *reinterpret_cast<float2*>(out + ((b0 + row) * NT + 255) * 2) = v;
      }
    }
  }
}

extern "C" void kernel_launch(void* const* d_in, const int* in_sizes, int n_in,
                              void* d_out, int out_size, void* d_ws, size_t ws_size,
                              hipStream_t stream) {
  const float* x   = (const float*)d_in[0];
  const int*   a   = (const int*)d_in[1];
  const int*   tt  = (const int*)d_in[2];
  const float* y   = (const float*)d_in[3];
  // d_in[4] = mask: forward output is mask-independent (m*v + (1-m)*v == v)
  const float* eps = (const float*)d_in[5];
  const float* Wx  = (const float*)d_in[6];
  const float* bx  = (const float*)d_in[7];
  const float* Ea  = (const float*)d_in[8];
  const float* Et  = (const float*)d_in[9];
  const float* Wih = (const float*)d_in[10];
  const float* Whh = (const float*)d_in[11];
  const float* bih = (const float*)d_in[12];
  const float* bhh = (const float*)d_in[13];
  const float* W0  = (const float*)d_in[14];
  const float* b0  = (const float*)d_in[15];
  const float* Wy  = (const float*)d_in[16];
  const float* by  = (const float*)d_in[17];
  float* out = (float*)d_out;

  gru_kernel<<<NB / 16, 512, 0, stream>>>(x, a, tt, y, eps, Wx, bx, Ea, Et,
                                          Wih, Whh, bih, bhh, W0, b0, Wy, by, out);
}